// Round 5
// baseline (704.166 us; speedup 1.0000x reference)
//
#include <hip/hip_runtime.h>
#include <stdint.h>
#include <stddef.h>

typedef __bf16 bf16_t;
typedef __bf16 bf16x4 __attribute__((ext_vector_type(4)));
typedef __bf16 bf16x8 __attribute__((ext_vector_type(8)));
typedef float f32x4 __attribute__((ext_vector_type(4)));

#define DEV static __device__ __forceinline__

static constexpr int kB = 8, kT = 1024, kC = 1024, kM = 8192, kH = 16, kHD = 64, kFF = 4096;

DEV f32x4 mfma16(bf16x8 a, bf16x8 b, f32x4 c) {
  return __builtin_amdgcn_mfma_f32_16x16x32_bf16(a, b, c, 0, 0, 0);
}

// raw hardware exp2 (D = 2^S0). Inputs here are always <= 0 (or ~-3e38 masked),
// so no denormal-range pre-scaling is needed — avoids the ocml libcall expansion.
DEV float ex2(float x) {
  float r;
  asm("v_exp_f32 %0, %1" : "=v"(r) : "v"(x));
  return r;
}

// async global->LDS, 16B per lane. LDS dest must be wave-uniform base (+lane*16 by HW).
DEV void gload_lds16(const void* g, void* l) {
  __builtin_amdgcn_global_load_lds(
      reinterpret_cast<const __attribute__((address_space(1))) void*>(
          reinterpret_cast<uintptr_t>(g)),
      reinterpret_cast<__attribute__((address_space(3))) void*>(
          static_cast<uint32_t>(reinterpret_cast<uintptr_t>(l))),
      16, 0, 0);
}

// ---------------- cast f32 -> bf16 ----------------
__global__ void k_cast_bf16(const float* __restrict__ in, bf16_t* __restrict__ out, int n4) {
  int i = blockIdx.x * blockDim.x + threadIdx.x;
  if (i >= n4) return;
  float4 v = reinterpret_cast<const float4*>(in)[i];
  bf16x4 o;
  o[0] = (bf16_t)v.x; o[1] = (bf16_t)v.y; o[2] = (bf16_t)v.z; o[3] = (bf16_t)v.w;
  reinterpret_cast<bf16x4*>(out)[i] = o;
}

// ---------- transpose+cast f32[R][C] -> bf16[C][R] ----------
__global__ void k_transpose_cast(const float* __restrict__ in, bf16_t* __restrict__ out,
                                 int R, int C) {
  __shared__ float tile[32][33];
  int c0 = blockIdx.x * 32, r0 = blockIdx.y * 32;
  int tx = threadIdx.x, ty = threadIdx.y;  // (32,8)
#pragma unroll
  for (int i = 0; i < 4; ++i)
    tile[ty + 8 * i][tx] = in[(size_t)(r0 + ty + 8 * i) * C + c0 + tx];
  __syncthreads();
#pragma unroll
  for (int i = 0; i < 4; ++i)
    out[(size_t)(c0 + ty + 8 * i) * R + r0 + tx] = (bf16_t)tile[tx][ty + 8 * i];
}

// ---------------- layernorm f32 -> bf16 (one block per row of 1024) ----------------
// CASTX: also emit bf16 cast of the raw input row (fuses k_cast of x).
template <bool CASTX>
__global__ __launch_bounds__(256) void k_ln(const float* __restrict__ in,
                                            const float* __restrict__ g,
                                            const float* __restrict__ b,
                                            bf16_t* __restrict__ out,
                                            bf16_t* __restrict__ rawout) {
  int row = blockIdx.x, t = threadIdx.x;
  const float4 v = reinterpret_cast<const float4*>(in + (size_t)row * kC)[t];
  if constexpr (CASTX) {
    bf16x4 c;
    c[0] = (bf16_t)v.x; c[1] = (bf16_t)v.y; c[2] = (bf16_t)v.z; c[3] = (bf16_t)v.w;
    reinterpret_cast<bf16x4*>(rawout + (size_t)row * kC)[t] = c;
  }
  float s = v.x + v.y + v.z + v.w;
  float ss = v.x * v.x + v.y * v.y + v.z * v.z + v.w * v.w;
#pragma unroll
  for (int off = 1; off < 64; off <<= 1) {
    s += __shfl_xor(s, off, 64);
    ss += __shfl_xor(ss, off, 64);
  }
  __shared__ float rs[4], rss[4];
  int w = t >> 6;
  if ((t & 63) == 0) { rs[w] = s; rss[w] = ss; }
  __syncthreads();
  s = rs[0] + rs[1] + rs[2] + rs[3];
  ss = rss[0] + rss[1] + rss[2] + rss[3];
  float mean = s * (1.f / kC);
  float var = ss * (1.f / kC) - mean * mean;
  float rstd = rsqrtf(var + 1e-5f);
  float4 gv = reinterpret_cast<const float4*>(g)[t];
  float4 bv = reinterpret_cast<const float4*>(b)[t];
  bf16x4 o;
  o[0] = (bf16_t)((v.x - mean) * rstd * gv.x + bv.x);
  o[1] = (bf16_t)((v.y - mean) * rstd * gv.y + bv.y);
  o[2] = (bf16_t)((v.z - mean) * rstd * gv.z + bv.z);
  o[3] = (bf16_t)((v.w - mean) * rstd * gv.w + bv.w);
  reinterpret_cast<bf16x4*>(out + (size_t)row * kC)[t] = o;
}

// ---------------- GEMM: C[M,N] = A[M,K] @ Bt[N,K]^T  (both bf16, K-contig rows) --------
// EPI: 0 = bf16 out; 1 = f32 out + bias + residual; 2 = bf16 out + bias + ReLU;
//      3 = bf16 TRANSPOSED out (out[c][tok], leading dim M) — for V^T
template <int EPI>
__global__ __launch_bounds__(256, 2) void k_gemm_bt(
    const bf16_t* __restrict__ A, const bf16_t* __restrict__ Bt,
    const float* __restrict__ bias, const float* __restrict__ res,
    float* __restrict__ outf, bf16_t* __restrict__ outb, int M, int N, int K) {
  __shared__ bf16_t As[128 * 32];
  __shared__ bf16_t Bs[128 * 32];
  const int t = threadIdx.x;
  const int w = t >> 6, lane = t & 63;
  const int l15 = lane & 15, l4 = lane >> 4;
  const int m0 = blockIdx.y * 128, n0 = blockIdx.x * 128;
  const int wm = (w >> 1) * 64, wn = (w & 1) * 64;  // 2x2 wave grid, 64x64 per wave
  f32x4 acc[4][4] = {};

  const int srow = t >> 2;            // row within 64-row half
  const int scol = (t & 3) * 16;      // byte offset within 64B (=32 bf16) row
  const char* Ab = (const char*)A + ((size_t)(m0 + srow) * K) * 2 + scol;
  const char* Bb = (const char*)Bt + ((size_t)(n0 + srow) * K) * 2 + scol;
  const size_t rstep = (size_t)64 * K * 2;  // +64 rows in bytes
  char* AsB = (char*)As;
  char* BsB = (char*)Bs;

  for (int k0 = 0; k0 < K; k0 += 32) {
    const size_t kb = (size_t)k0 * 2;
    gload_lds16(Ab + kb,         AsB + w * 1024);
    gload_lds16(Ab + kb + rstep, AsB + 4096 + w * 1024);
    gload_lds16(Bb + kb,         BsB + w * 1024);
    gload_lds16(Bb + kb + rstep, BsB + 4096 + w * 1024);
    __syncthreads();  // drains vmcnt -> tiles visible
    bf16x8 af[4], bfr[4];
#pragma unroll
    for (int m = 0; m < 4; ++m)
      af[m] = *reinterpret_cast<const bf16x8*>(&As[(wm + m * 16 + l15) * 32 + l4 * 8]);
#pragma unroll
    for (int n = 0; n < 4; ++n)
      bfr[n] = *reinterpret_cast<const bf16x8*>(&Bs[(wn + n * 16 + l15) * 32 + l4 * 8]);
#pragma unroll
    for (int m = 0; m < 4; ++m)
#pragma unroll
      for (int n = 0; n < 4; ++n)
        acc[m][n] = mfma16(af[m], bfr[n], acc[m][n]);
    __syncthreads();  // protect LDS from next-iter staging
  }

  const int gm = m0 + wm + l4 * 4;
  const int gn = n0 + wn + l15;
  if constexpr (EPI == 0) {
#pragma unroll
    for (int m = 0; m < 4; ++m)
#pragma unroll
      for (int n = 0; n < 4; ++n)
#pragma unroll
        for (int r = 0; r < 4; ++r)
          outb[(size_t)(gm + m * 16 + r) * N + (gn + n * 16)] = (bf16_t)acc[m][n][r];
  } else if constexpr (EPI == 1) {
#pragma unroll
    for (int m = 0; m < 4; ++m)
#pragma unroll
      for (int n = 0; n < 4; ++n) {
        const int col = gn + n * 16;
        const float bv = bias[col];
#pragma unroll
        for (int r = 0; r < 4; ++r) {
          const size_t idx = (size_t)(gm + m * 16 + r) * N + col;
          outf[idx] = acc[m][n][r] + bv + res[idx];
        }
      }
  } else if constexpr (EPI == 2) {
#pragma unroll
    for (int m = 0; m < 4; ++m)
#pragma unroll
      for (int n = 0; n < 4; ++n) {
        const int col = gn + n * 16;
        const float bv = bias[col];
#pragma unroll
        for (int r = 0; r < 4; ++r) {
          float v = acc[m][n][r] + bv;
          v = fmaxf(v, 0.f);
          outb[(size_t)(gm + m * 16 + r) * N + col] = (bf16_t)v;
        }
      }
  } else {  // EPI == 3: transposed bf16 store (rows of acc are contiguous in out)
#pragma unroll
    for (int m = 0; m < 4; ++m)
#pragma unroll
      for (int n = 0; n < 4; ++n) {
        bf16x4 ov;
#pragma unroll
        for (int r = 0; r < 4; ++r) ov[r] = (bf16_t)acc[m][n][r];
        *reinterpret_cast<bf16x4*>(&outb[(size_t)(gn + n * 16) * M + gm + m * 16]) = ov;
      }
  }
}

// ---------------- flash attention (swapped-operand, single-wave blocks) ----------------
// Grid (b, h, qi): one 64-lane wave per block, 32 q-rows, 64-key tiles.
// S^T = mfma(K,Q): lane owns one q-row per fragment -> softmax state lane-local.
// Row-sums via ones-MFMA (po_s accumulates sum(P) per q-row; uniform across l4).
// K double-buffered in LDS via global_load_lds (prefetch tile kt+1 under tile kt's
// softmax+PV); raw v_exp_f32 for exp2.
template <bool CAUSAL>
__global__ __launch_bounds__(64) void k_attn(const bf16_t* __restrict__ Q,
                                             const bf16_t* __restrict__ Kb,
                                             const bf16_t* __restrict__ Vt,
                                             bf16_t* __restrict__ O) {
  __shared__ bf16x8 Ks[2][512];   // K staging: 2 bufs x 8KB (instr j block = 64 lanes x 16B)
  __shared__ bf16_t P[32][72];    // P buffer: [q-row][key], 144B rows
  const int b = blockIdx.x, h = blockIdx.y, qi = blockIdx.z;
  const int lane = threadIdx.x;
  const int l15 = lane & 15, l4 = lane >> 4;
  const int qr0 = qi * 32;

  // Q fragments (B-operand: row=l15=q-row, k=l4*8+j), scale 1/8 * log2(e) folded in.
  bf16x8 qf[2][2];
#pragma unroll
  for (int a = 0; a < 2; ++a) {
    const bf16_t* qp = Q + (size_t)(b * kT + qr0 + a * 16 + l15) * kC + h * kHD + l4 * 8;
    qf[a][0] = *reinterpret_cast<const bf16x8*>(qp);
    qf[a][1] = *reinterpret_cast<const bf16x8*>(qp + 32);
#pragma unroll
    for (int j = 0; j < 8; ++j) {
      qf[a][0][j] = (bf16_t)((float)qf[a][0][j] * 0.1803368801111204f);
      qf[a][1][j] = (bf16_t)((float)qf[a][1][j] * 0.1803368801111204f);
    }
  }
  bf16x8 ones;
#pragma unroll
  for (int j = 0; j < 8; ++j) ones[j] = (bf16_t)1.0f;

  f32x4 po[2][4] = {};   // O^T accum: po[a][n], row=d-in-chunk, col(l15)=q-row
  f32x4 po_s[2] = {};    // sum(P) accum via ones-MFMA (all rows identical)
  float mrun[2];
  mrun[0] = mrun[1] = -3.0e38f;

  const int nkt = CAUSAL ? (qr0 + 31) / 64 + 1 : (kT / 64);
  // per-lane base pointers
  const bf16_t* kp = Kb + (size_t)(b * kT + l15) * kC + h * kHD + l4 * 8;
  const bf16_t* vp = Vt + (size_t)(h * kHD + l15) * (kB * kT) + (size_t)b * kT + l4 * 8;

  // prologue: stage K(0) into buf0, read into regs
  bf16x8 kf[4][2];
#pragma unroll
  for (int j = 0; j < 8; ++j)
    gload_lds16(kp + (size_t)(j >> 1) * 16 * kC + (j & 1) * 32, (void*)&Ks[0][j * 64]);
  asm volatile("s_waitcnt vmcnt(0)" ::: "memory");
#pragma unroll
  for (int j = 0; j < 8; ++j) kf[j >> 1][j & 1] = Ks[0][j * 64 + lane];

  const bf16_t* kpn = kp + (size_t)64 * kC;  // next-tile K base
  int cur = 0;

  for (int kt = 0; kt < nkt; ++kt, vp += 64, kpn += (size_t)64 * kC) {
    const bool pre = (kt + 1 < nkt);
    // prefetch K(kt+1) -> other LDS buffer (async DMA, no VGPR cost)
    if (pre) {
#pragma unroll
      for (int j = 0; j < 8; ++j)
        gload_lds16(kpn + (size_t)(j >> 1) * 16 * kC + (j & 1) * 32,
                    (void*)&Ks[cur ^ 1][j * 64]);
    }
    // V fragments — independent of softmax; issue early so latency hides under it
    bf16x8 vf[2][4];
#pragma unroll
    for (int kk = 0; kk < 2; ++kk)
#pragma unroll
      for (int n = 0; n < 4; ++n)
        vf[kk][n] = *reinterpret_cast<const bf16x8*>(
            vp + (size_t)(n * 16) * (kB * kT) + kk * 32);

    // S^T[key, q] : s[a][sub], col(l15)=q-row, row(l4*4+r)=key
    f32x4 s[2][4] = {};
    __builtin_amdgcn_s_setprio(1);
#pragma unroll
    for (int a = 0; a < 2; ++a)
#pragma unroll
      for (int sub = 0; sub < 4; ++sub) {
        s[a][sub] = mfma16(kf[sub][0], qf[a][0], s[a][sub]);
        s[a][sub] = mfma16(kf[sub][1], qf[a][1], s[a][sub]);
      }
    __builtin_amdgcn_s_setprio(0);
    if (CAUSAL && kt == nkt - 1) {
#pragma unroll
      for (int a = 0; a < 2; ++a) {
        const int qrow = qr0 + a * 16 + l15;
#pragma unroll
        for (int sub = 0; sub < 4; ++sub)
#pragma unroll
          for (int r = 0; r < 4; ++r) {
            const int key = kt * 64 + sub * 16 + l4 * 4 + r;
            if (key > qrow) s[a][sub][r] = -3.0e38f;
          }
      }
    }
#pragma unroll
    for (int a = 0; a < 2; ++a) {
      // tree max (short dep chain) + 2 shfl over the l4 groups
      float t0 = fmaxf(fmaxf(s[a][0][0], s[a][0][1]), fmaxf(s[a][0][2], s[a][0][3]));
      float t1 = fmaxf(fmaxf(s[a][1][0], s[a][1][1]), fmaxf(s[a][1][2], s[a][1][3]));
      float t2 = fmaxf(fmaxf(s[a][2][0], s[a][2][1]), fmaxf(s[a][2][2], s[a][2][3]));
      float t3 = fmaxf(fmaxf(s[a][3][0], s[a][3][1]), fmaxf(s[a][3][2], s[a][3][3]));
      float v = fmaxf(fmaxf(t0, t1), fmaxf(t2, t3));
      v = fmaxf(v, __shfl_xor(v, 16, 64));
      v = fmaxf(v, __shfl_xor(v, 32, 64));
      // defer-max: only rescale when some row grew past m+8 (P bounded by 2^8)
      if (!__all(v <= mrun[a] + 8.f)) {
        const float mnew = fmaxf(mrun[a], v);
        const float corr = ex2(mrun[a] - mnew);
        mrun[a] = mnew;
#pragma unroll
        for (int n = 0; n < 4; ++n)
#pragma unroll
          for (int r = 0; r < 4; ++r) po[a][n][r] *= corr;
#pragma unroll
        for (int r = 0; r < 4; ++r) po_s[a][r] *= corr;
      }
      // P = exp2(s - m) via raw v_exp_f32; pack 4 per sub, store to LDS (8B writes)
#pragma unroll
      for (int sub = 0; sub < 4; ++sub) {
        bf16x4 pk;
#pragma unroll
        for (int r = 0; r < 4; ++r) pk[r] = (bf16_t)ex2(s[a][sub][r] - mrun[a]);
        *reinterpret_cast<bf16x4*>(&P[a * 16 + l15][sub * 16 + l4 * 4]) = pk;
      }
    }
    // PV: O^T += V^T * P ; row-sums += ones * P  (A=frag row=l15, B=P frag)
#pragma unroll
    for (int a = 0; a < 2; ++a)
#pragma unroll
      for (int kk = 0; kk < 2; ++kk) {
        const bf16x8 pf =
            *reinterpret_cast<const bf16x8*>(&P[a * 16 + l15][kk * 32 + l4 * 8]);
        __builtin_amdgcn_s_setprio(1);
#pragma unroll
        for (int n = 0; n < 4; ++n) po[a][n] = mfma16(vf[kk][n], pf, po[a][n]);
        po_s[a] = mfma16(ones, pf, po_s[a]);
        __builtin_amdgcn_s_setprio(0);
      }
    // load next K tile from the prefetched LDS buffer
    if (pre) {
      asm volatile("s_waitcnt vmcnt(0)" ::: "memory");
#pragma unroll
      for (int j = 0; j < 8; ++j) kf[j >> 1][j & 1] = Ks[cur ^ 1][j * 64 + lane];
      cur ^= 1;
    }
  }
#pragma unroll
  for (int a = 0; a < 2; ++a) {
    const float inv = 1.f / po_s[a][0];  // uniform across l4 (all D-rows identical)
#pragma unroll
    for (int n = 0; n < 4; ++n) {
      bf16x4 ov;
#pragma unroll
      for (int r = 0; r < 4; ++r) ov[r] = (bf16_t)(po[a][n][r] * inv);
      *reinterpret_cast<bf16x4*>(
          O + (size_t)(b * kT + qr0 + a * 16 + l15) * kC + h * kHD + n * 16 + l4 * 4) = ov;
    }
  }
}

// ---------------- launcher ----------------
extern "C" void kernel_launch(void* const* d_in, const int* in_sizes, int n_in,
                              void* d_out, int out_size, void* d_ws, size_t ws_size,
                              hipStream_t stream) {
  const float* x      = (const float*)d_in[0];
  const float* enc    = (const float*)d_in[1];
  const float* sa_wq  = (const float*)d_in[2];
  const float* sa_wk  = (const float*)d_in[3];
  const float* sa_wv  = (const float*)d_in[4];
  const float* sa_pw  = (const float*)d_in[5];
  const float* sa_pb  = (const float*)d_in[6];
  const float* ca_wq  = (const float*)d_in[7];
  const float* ca_wk  = (const float*)d_in[8];
  const float* ca_wv  = (const float*)d_in[9];
  const float* ca_pw  = (const float*)d_in[10];
  const float* ca_pb  = (const float*)d_in[11];
  const float* ff_w1  = (const float*)d_in[12];
  const float* ff_b1  = (const float*)d_in[13];
  const float* ff_w2  = (const float*)d_in[14];
  const float* ff_b2  = (const float*)d_in[15];
  const float* ln1_g  = (const float*)d_in[16];
  const float* ln1_b  = (const float*)d_in[17];
  const float* ln2_g  = (const float*)d_in[18];
  const float* ln2_b  = (const float*)d_in[19];
  const float* ln3_g  = (const float*)d_in[20];
  const float* ln3_b  = (const float*)d_in[21];

  const size_t ACT_BF = (size_t)kM * kC * 2;   // 16 MiB
  const size_t ACT_F  = (size_t)kM * kC * 4;   // 32 MiB
  const size_t W_BF   = (size_t)kC * kC * 2;
  const size_t FF_BF  = (size_t)kC * kFF * 2;
  const size_t H_BF   = (size_t)kM * kFF * 2;

  char* ws = (char*)d_ws;
  size_t off = 0;
  auto alloc = [&](size_t bytes) {
    char* p = ws + off;
    off += (bytes + 255) & ~(size_t)255;
    return p;
  };
  bf16_t* xbf   = (bf16_t*)alloc(ACT_BF);
  bf16_t* encbf = (bf16_t*)alloc(ACT_BF);
  bf16_t* lnbuf = (bf16_t*)alloc(ACT_BF);
  bf16_t* wsaq  = (bf16_t*)alloc(W_BF);
  bf16_t* wsak  = (bf16_t*)alloc(W_BF);
  bf16_t* wsav  = (bf16_t*)alloc(W_BF);
  bf16_t* wsap  = (bf16_t*)alloc(W_BF);
  bf16_t* wcaq  = (bf16_t*)alloc(W_BF);
  bf16_t* wcak  = (bf16_t*)alloc(W_BF);
  bf16_t* wcav  = (bf16_t*)alloc(W_BF);
  bf16_t* wcap  = (bf16_t*)alloc(W_BF);
  bf16_t* wff1t = (bf16_t*)alloc(FF_BF);   // [4096][1024]
  bf16_t* wff2t = (bf16_t*)alloc(FF_BF);   // [1024][4096]
  float*  rbuf  = (float*)alloc(ACT_F);    // residual chain (f32)
  char*   scr   = alloc(5 * ACT_BF > H_BF ? 5 * ACT_BF : H_BF);
  bf16_t* qbf   = (bf16_t*)scr;
  bf16_t* kbf   = (bf16_t*)(scr + ACT_BF);
  bf16_t* vtbf  = (bf16_t*)(scr + 3 * ACT_BF);
  bf16_t* aobf  = (bf16_t*)(scr + 4 * ACT_BF);
  bf16_t* hbf   = (bf16_t*)scr;            // FFN hidden reuses q..ao region

  const dim3 blk256(256), blk64(64), blkT(32, 8);
  const int n4 = kM * kC / 4;
  const dim3 gGemmC(kC / 128, kM / 128);    // (8, 64)
  const dim3 gGemmF(kFF / 128, kM / 128);   // (32, 64)
  const dim3 gAttn(kB, kH, kT / 32);        // (8, 16, 32) — 1 wave/block, XCD-friendly

  // ---- input casts + weight transposes ----
  k_cast_bf16<<<n4 / 256, blk256, 0, stream>>>(enc, encbf, n4);
  k_transpose_cast<<<dim3(kC / 32, kC / 32), blkT, 0, stream>>>(sa_wq, wsaq, kC, kC);
  k_transpose_cast<<<dim3(kC / 32, kC / 32), blkT, 0, stream>>>(sa_wk, wsak, kC, kC);
  k_transpose_cast<<<dim3(kC / 32, kC / 32), blkT, 0, stream>>>(sa_wv, wsav, kC, kC);
  k_transpose_cast<<<dim3(kC / 32, kC / 32), blkT, 0, stream>>>(sa_pw, wsap, kC, kC);
  k_transpose_cast<<<dim3(kC / 32, kC / 32), blkT, 0, stream>>>(ca_wq, wcaq, kC, kC);
  k_transpose_cast<<<dim3(kC / 32, kC / 32), blkT, 0, stream>>>(ca_wk, wcak, kC, kC);
  k_transpose_cast<<<dim3(kC / 32, kC / 32), blkT, 0, stream>>>(ca_wv, wcav, kC, kC);
  k_transpose_cast<<<dim3(kC / 32, kC / 32), blkT, 0, stream>>>(ca_pw, wcap, kC, kC);
  k_transpose_cast<<<dim3(kFF / 32, kC / 32), blkT, 0, stream>>>(ff_w1, wff1t, kC, kFF);
  k_transpose_cast<<<dim3(kC / 32, kFF / 32), blkT, 0, stream>>>(ff_w2, wff2t, kFF, kC);

  // ---- self-attention (q from ln1(x), k/v from raw x, causal) ----
  k_ln<true><<<kM, blk256, 0, stream>>>(x, ln1_g, ln1_b, lnbuf, xbf);
  k_gemm_bt<0><<<gGemmC, blk256, 0, stream>>>(lnbuf, wsaq, nullptr, nullptr, nullptr, qbf, kM, kC, kC);
  k_gemm_bt<0><<<gGemmC, blk256, 0, stream>>>(xbf,   wsak, nullptr, nullptr, nullptr, kbf, kM, kC, kC);
  k_gemm_bt<3><<<gGemmC, blk256, 0, stream>>>(xbf,   wsav, nullptr, nullptr, nullptr, vtbf, kM, kC, kC);
  k_attn<true><<<gAttn, blk64, 0, stream>>>(qbf, kbf, vtbf, aobf);
  k_gemm_bt<1><<<gGemmC, blk256, 0, stream>>>(aobf, wsap, sa_pb, x, rbuf, nullptr, kM, kC, kC);

  // ---- cross-attention (q from ln2(r), k/v from encoder_output) ----
  k_ln<false><<<kM, blk256, 0, stream>>>(rbuf, ln2_g, ln2_b, lnbuf, nullptr);
  k_gemm_bt<0><<<gGemmC, blk256, 0, stream>>>(lnbuf, wcaq, nullptr, nullptr, nullptr, qbf, kM, kC, kC);
  k_gemm_bt<0><<<gGemmC, blk256, 0, stream>>>(encbf, wcak, nullptr, nullptr, nullptr, kbf, kM, kC, kC);
  k_gemm_bt<3><<<gGemmC, blk256, 0, stream>>>(encbf, wcav, nullptr, nullptr, nullptr, vtbf, kM, kC, kC);
  k_attn<false><<<gAttn, blk64, 0, stream>>>(qbf, kbf, vtbf, aobf);
  k_gemm_bt<1><<<gGemmC, blk256, 0, stream>>>(aobf, wcap, ca_pb, rbuf, rbuf, nullptr, kM, kC, kC);

  // ---- feed-forward ----
  k_ln<false><<<kM, blk256, 0, stream>>>(rbuf, ln3_g, ln3_b, lnbuf, nullptr);
  k_gemm_bt<2><<<gGemmF, blk256, 0, stream>>>(lnbuf, wff1t, ff_b1, nullptr, nullptr, hbf, kM, kFF, kC);
  k_gemm_bt<1><<<gGemmC, blk256, 0, stream>>>(hbf, wff2t, ff_b2, rbuf, (float*)d_out, nullptr, kM, kC, kFF);

  (void)in_sizes; (void)n_in; (void)out_size; (void)ws_size;
}

// Round 6
// 614.023 us; speedup vs baseline: 1.1468x; 1.1468x over previous
//
#include <hip/hip_runtime.h>
#include <stdint.h>
#include <stddef.h>

typedef __bf16 bf16_t;
typedef __bf16 bf16x4 __attribute__((ext_vector_type(4)));
typedef __bf16 bf16x8 __attribute__((ext_vector_type(8)));
typedef float f32x4 __attribute__((ext_vector_type(4)));

#define DEV static __device__ __forceinline__

static constexpr int kB = 8, kT = 1024, kC = 1024, kM = 8192, kH = 16, kHD = 64, kFF = 4096;

DEV f32x4 mfma16(bf16x8 a, bf16x8 b, f32x4 c) {
  return __builtin_amdgcn_mfma_f32_16x16x32_bf16(a, b, c, 0, 0, 0);
}

// raw hardware exp2 (D = 2^S0); inputs always <= 0 here.
DEV float ex2(float x) {
  float r;
  asm("v_exp_f32 %0, %1" : "=v"(r) : "v"(x));
  return r;
}

// async global->LDS, 16B per lane. LDS dest must be wave-uniform base (+lane*16 by HW).
DEV void gload_lds16(const void* g, void* l) {
  __builtin_amdgcn_global_load_lds(
      reinterpret_cast<const __attribute__((address_space(1))) void*>(
          reinterpret_cast<uintptr_t>(g)),
      reinterpret_cast<__attribute__((address_space(3))) void*>(
          static_cast<uint32_t>(reinterpret_cast<uintptr_t>(l))),
      16, 0, 0);
}

// ---------------- cast f32 -> bf16 ----------------
__global__ void k_cast_bf16(const float* __restrict__ in, bf16_t* __restrict__ out, int n4) {
  int i = blockIdx.x * blockDim.x + threadIdx.x;
  if (i >= n4) return;
  float4 v = reinterpret_cast<const float4*>(in)[i];
  bf16x4 o;
  o[0] = (bf16_t)v.x; o[1] = (bf16_t)v.y; o[2] = (bf16_t)v.z; o[3] = (bf16_t)v.w;
  reinterpret_cast<bf16x4*>(out)[i] = o;
}

// ---------- transpose+cast f32[R][C] -> bf16[C][R] ----------
__global__ void k_transpose_cast(const float* __restrict__ in, bf16_t* __restrict__ out,
                                 int R, int C) {
  __shared__ float tile[32][33];
  int c0 = blockIdx.x * 32, r0 = blockIdx.y * 32;
  int tx = threadIdx.x, ty = threadIdx.y;  // (32,8)
#pragma unroll
  for (int i = 0; i < 4; ++i)
    tile[ty + 8 * i][tx] = in[(size_t)(r0 + ty + 8 * i) * C + c0 + tx];
  __syncthreads();
#pragma unroll
  for (int i = 0; i < 4; ++i)
    out[(size_t)(c0 + ty + 8 * i) * R + r0 + tx] = (bf16_t)tile[tx][ty + 8 * i];
}

// ---------------- layernorm f32 -> bf16 (one block per row of 1024) ----------------
template <bool CASTX>
__global__ __launch_bounds__(256) void k_ln(const float* __restrict__ in,
                                            const float* __restrict__ g,
                                            const float* __restrict__ b,
                                            bf16_t* __restrict__ out,
                                            bf16_t* __restrict__ rawout) {
  int row = blockIdx.x, t = threadIdx.x;
  const float4 v = reinterpret_cast<const float4*>(in + (size_t)row * kC)[t];
  if constexpr (CASTX) {
    bf16x4 c;
    c[0] = (bf16_t)v.x; c[1] = (bf16_t)v.y; c[2] = (bf16_t)v.z; c[3] = (bf16_t)v.w;
    reinterpret_cast<bf16x4*>(rawout + (size_t)row * kC)[t] = c;
  }
  float s = v.x + v.y + v.z + v.w;
  float ss = v.x * v.x + v.y * v.y + v.z * v.z + v.w * v.w;
#pragma unroll
  for (int off = 1; off < 64; off <<= 1) {
    s += __shfl_xor(s, off, 64);
    ss += __shfl_xor(ss, off, 64);
  }
  __shared__ float rs[4], rss[4];
  int w = t >> 6;
  if ((t & 63) == 0) { rs[w] = s; rss[w] = ss; }
  __syncthreads();
  s = rs[0] + rs[1] + rs[2] + rs[3];
  ss = rss[0] + rss[1] + rss[2] + rss[3];
  float mean = s * (1.f / kC);
  float var = ss * (1.f / kC) - mean * mean;
  float rstd = rsqrtf(var + 1e-5f);
  float4 gv = reinterpret_cast<const float4*>(g)[t];
  float4 bv = reinterpret_cast<const float4*>(b)[t];
  bf16x4 o;
  o[0] = (bf16_t)((v.x - mean) * rstd * gv.x + bv.x);
  o[1] = (bf16_t)((v.y - mean) * rstd * gv.y + bv.y);
  o[2] = (bf16_t)((v.z - mean) * rstd * gv.z + bv.z);
  o[3] = (bf16_t)((v.w - mean) * rstd * gv.w + bv.w);
  reinterpret_cast<bf16x4*>(out + (size_t)row * kC)[t] = o;
}

// ============ GEMM v2: C[M,N] = A[M,K] @ Bt[N,K]^T ============
// BM=128, BN=256, BK=64, 8 waves (2Mx4N, 64x64 each), ring-3 LDS (144KB dynamic),
// counted-vmcnt pipeline: stage tile t+2 while computing tile t; s_waitcnt vmcnt(6)
// at tile boundary (never drain to 0 in steady state); 1 barrier per K-tile.
// LDS XOR-swizzle: colbyte ^= (row&7)<<4 (both-sides involution: pre-swizzled
// global source for global_load_lds + swizzled ds_read) -> conflict-free b128 reads.
// EPI: 0 = bf16 out; 1 = f32 out + bias + residual; 2 = bf16 out + bias + ReLU;
//      3 = bf16 TRANSPOSED out (out[col][row], leading dim M)
template <int EPI>
__global__ __launch_bounds__(512, 2) void k_gemm2(
    const bf16_t* __restrict__ A, const bf16_t* __restrict__ Bt,
    const float* __restrict__ bias, const float* __restrict__ res,
    float* __restrict__ outf, bf16_t* __restrict__ outb, int M, int N, int K) {
  extern __shared__ bf16_t smem[];
  bf16_t* As = smem;                  // 3 x 128x64  (8192 el / buf)
  bf16_t* Bs = smem + 3 * 8192;       // 3 x 256x64  (16384 el / buf)
  const int t = threadIdx.x;
  const int w = t >> 6, lane = t & 63;
  const int l15 = lane & 15, l4 = lane >> 4;
  const int wr = w >> 2, wc = w & 3;
  const int bm0 = blockIdx.y * 128, bn0 = blockIdx.x * 256;

  f32x4 acc[4][4] = {};

  // staging source: per instr r, row = r*64 + w*8 + (lane>>3), col_el = ((lane&7)^(lane>>3))*8
  const int srow = w * 8 + (lane >> 3);
  const int scol = ((lane & 7) ^ (lane >> 3)) * 8;
  const bf16_t* aSrc0 = A + (size_t)(bm0 + srow) * K + scol;
  const bf16_t* bSrc0 = Bt + (size_t)(bn0 + srow) * K + scol;
  const size_t r64 = (size_t)64 * K;

  // read-side: a row = wr*64 + m*16 + l15 ; b row = wc*64 + n*16 + l15 ;
  // col_el = ((h*64 + l4*16) ^ ((l15&7)*16)) / 2
  const int arow = wr * 64 + l15;
  const int brow = wc * 64 + l15;
  const int cbx = (l15 & 7) * 16;
  const int cbe0 = ((l4 * 16) ^ cbx) >> 1;
  const int cbe1 = ((64 | (l4 * 16)) ^ cbx) >> 1;

  const int nkt = K >> 6;

  auto stage = [&](int tt, int bi) {
    const size_t ko = (size_t)tt * 64;
    bf16_t* da = As + bi * 8192;
    bf16_t* db = Bs + bi * 16384;
    gload_lds16(aSrc0 + ko,            da + w * 512);
    gload_lds16(aSrc0 + ko + r64,      da + 4096 + w * 512);
    gload_lds16(bSrc0 + ko,            db + w * 512);
    gload_lds16(bSrc0 + ko + r64,      db + 4096 + w * 512);
    gload_lds16(bSrc0 + ko + 2 * r64,  db + 8192 + w * 512);
    gload_lds16(bSrc0 + ko + 3 * r64,  db + 12288 + w * 512);
  };

  // prologue: stage tiles 0,1; force tile 0 complete (leave tile 1 in flight)
  stage(0, 0);
  stage(1, 1);
  asm volatile("s_waitcnt vmcnt(6)" ::: "memory");
  __builtin_amdgcn_s_barrier();

  int bi = 0, bs = 2;
  for (int tt = 0; tt < nkt; ++tt) {
    if (tt + 2 < nkt) stage(tt + 2, bs);
    const bf16_t* bA = As + bi * 8192;
    const bf16_t* bB = Bs + bi * 16384;
    bf16x8 af[4], bfr[4];
    // phase 0: k-half 0
#pragma unroll
    for (int m = 0; m < 4; ++m)
      af[m] = *reinterpret_cast<const bf16x8*>(&bA[(arow + m * 16) * 64 + cbe0]);
#pragma unroll
    for (int n = 0; n < 4; ++n)
      bfr[n] = *reinterpret_cast<const bf16x8*>(&bB[(brow + n * 16) * 64 + cbe0]);
    __builtin_amdgcn_s_setprio(1);
#pragma unroll
    for (int m = 0; m < 4; ++m)
#pragma unroll
      for (int n = 0; n < 4; ++n) acc[m][n] = mfma16(af[m], bfr[n], acc[m][n]);
    __builtin_amdgcn_s_setprio(0);
    // phase 1: k-half 1
#pragma unroll
    for (int m = 0; m < 4; ++m)
      af[m] = *reinterpret_cast<const bf16x8*>(&bA[(arow + m * 16) * 64 + cbe1]);
#pragma unroll
    for (int n = 0; n < 4; ++n)
      bfr[n] = *reinterpret_cast<const bf16x8*>(&bB[(brow + n * 16) * 64 + cbe1]);
    __builtin_amdgcn_s_setprio(1);
#pragma unroll
    for (int m = 0; m < 4; ++m)
#pragma unroll
      for (int n = 0; n < 4; ++n) acc[m][n] = mfma16(af[m], bfr[n], acc[m][n]);
    __builtin_amdgcn_s_setprio(0);
    // tile boundary: force tile t+1's loads complete; leave tile t+2's in flight
    if (tt + 1 < nkt) {
      if (tt + 2 < nkt) asm volatile("s_waitcnt vmcnt(6)" ::: "memory");
      else              asm volatile("s_waitcnt vmcnt(0)" ::: "memory");
      __builtin_amdgcn_s_barrier();
    }
    bi = (bi == 2) ? 0 : bi + 1;
    bs = (bs == 2) ? 0 : bs + 1;
  }

  const int gm = bm0 + wr * 64 + l4 * 4;
  const int gn = bn0 + wc * 64 + l15;
  if constexpr (EPI == 0) {
#pragma unroll
    for (int m = 0; m < 4; ++m)
#pragma unroll
      for (int n = 0; n < 4; ++n)
#pragma unroll
        for (int r = 0; r < 4; ++r)
          outb[(size_t)(gm + m * 16 + r) * N + (gn + n * 16)] = (bf16_t)acc[m][n][r];
  } else if constexpr (EPI == 1) {
#pragma unroll
    for (int m = 0; m < 4; ++m)
#pragma unroll
      for (int n = 0; n < 4; ++n) {
        const int col = gn + n * 16;
        const float bv = bias[col];
#pragma unroll
        for (int r = 0; r < 4; ++r) {
          const size_t idx = (size_t)(gm + m * 16 + r) * N + col;
          outf[idx] = acc[m][n][r] + bv + res[idx];
        }
      }
  } else if constexpr (EPI == 2) {
#pragma unroll
    for (int m = 0; m < 4; ++m)
#pragma unroll
      for (int n = 0; n < 4; ++n) {
        const int col = gn + n * 16;
        const float bv = bias[col];
#pragma unroll
        for (int r = 0; r < 4; ++r) {
          float v = acc[m][n][r] + bv;
          v = fmaxf(v, 0.f);
          outb[(size_t)(gm + m * 16 + r) * N + col] = (bf16_t)v;
        }
      }
  } else {  // EPI == 3: transposed bf16 store
#pragma unroll
    for (int m = 0; m < 4; ++m)
#pragma unroll
      for (int n = 0; n < 4; ++n) {
        bf16x4 ov;
#pragma unroll
        for (int r = 0; r < 4; ++r) ov[r] = (bf16_t)acc[m][n][r];
        *reinterpret_cast<bf16x4*>(&outb[(size_t)(gn + n * 16) * M + gm + m * 16]) = ov;
      }
  }
}

// ---------------- flash attention (swapped-operand, single-wave blocks) ----------------
// R4 structure (direct-to-VGPR K loads) + v_exp_f32 + ones-MFMA row sums.
template <bool CAUSAL>
__global__ __launch_bounds__(64) void k_attn(const bf16_t* __restrict__ Q,
                                             const bf16_t* __restrict__ Kb,
                                             const bf16_t* __restrict__ Vt,
                                             bf16_t* __restrict__ O) {
  __shared__ bf16_t P[32][72];  // P buffer: [q-row][key], 144B rows
  const int b = blockIdx.x, h = blockIdx.y, qi = blockIdx.z;
  const int lane = threadIdx.x;
  const int l15 = lane & 15, l4 = lane >> 4;
  const int qr0 = qi * 32;

  bf16x8 qf[2][2];
#pragma unroll
  for (int a = 0; a < 2; ++a) {
    const bf16_t* qp = Q + (size_t)(b * kT + qr0 + a * 16 + l15) * kC + h * kHD + l4 * 8;
    qf[a][0] = *reinterpret_cast<const bf16x8*>(qp);
    qf[a][1] = *reinterpret_cast<const bf16x8*>(qp + 32);
#pragma unroll
    for (int j = 0; j < 8; ++j) {
      qf[a][0][j] = (bf16_t)((float)qf[a][0][j] * 0.1803368801111204f);
      qf[a][1][j] = (bf16_t)((float)qf[a][1][j] * 0.1803368801111204f);
    }
  }
  bf16x8 ones;
#pragma unroll
  for (int j = 0; j < 8; ++j) ones[j] = (bf16_t)1.0f;

  f32x4 po[2][4] = {};
  f32x4 po_s[2] = {};
  float mrun[2];
  mrun[0] = mrun[1] = -3.0e38f;

  const int nkt = CAUSAL ? (qr0 + 31) / 64 + 1 : (kT / 64);
  const bf16_t* kp = Kb + (size_t)(b * kT + l15) * kC + h * kHD + l4 * 8;
  const bf16_t* vp = Vt + (size_t)(h * kHD + l15) * (kB * kT) + (size_t)b * kT + l4 * 8;

  for (int kt = 0; kt < nkt; ++kt, kp += (size_t)64 * kC, vp += 64) {
    bf16x8 kf[4][2];
#pragma unroll
    for (int sub = 0; sub < 4; ++sub) {
      kf[sub][0] = *reinterpret_cast<const bf16x8*>(kp + (size_t)sub * 16 * kC);
      kf[sub][1] = *reinterpret_cast<const bf16x8*>(kp + (size_t)sub * 16 * kC + 32);
    }
    bf16x8 vf[2][4];
#pragma unroll
    for (int kk = 0; kk < 2; ++kk)
#pragma unroll
      for (int n = 0; n < 4; ++n)
        vf[kk][n] = *reinterpret_cast<const bf16x8*>(
            vp + (size_t)(n * 16) * (kB * kT) + kk * 32);

    f32x4 s[2][4] = {};
    __builtin_amdgcn_s_setprio(1);
#pragma unroll
    for (int a = 0; a < 2; ++a)
#pragma unroll
      for (int sub = 0; sub < 4; ++sub) {
        s[a][sub] = mfma16(kf[sub][0], qf[a][0], s[a][sub]);
        s[a][sub] = mfma16(kf[sub][1], qf[a][1], s[a][sub]);
      }
    __builtin_amdgcn_s_setprio(0);
    if (CAUSAL && kt == nkt - 1) {
#pragma unroll
      for (int a = 0; a < 2; ++a) {
        const int qrow = qr0 + a * 16 + l15;
#pragma unroll
        for (int sub = 0; sub < 4; ++sub)
#pragma unroll
          for (int r = 0; r < 4; ++r) {
            const int key = kt * 64 + sub * 16 + l4 * 4 + r;
            if (key > qrow) s[a][sub][r] = -3.0e38f;
          }
      }
    }
#pragma unroll
    for (int a = 0; a < 2; ++a) {
      float t0 = fmaxf(fmaxf(s[a][0][0], s[a][0][1]), fmaxf(s[a][0][2], s[a][0][3]));
      float t1 = fmaxf(fmaxf(s[a][1][0], s[a][1][1]), fmaxf(s[a][1][2], s[a][1][3]));
      float t2 = fmaxf(fmaxf(s[a][2][0], s[a][2][1]), fmaxf(s[a][2][2], s[a][2][3]));
      float t3 = fmaxf(fmaxf(s[a][3][0], s[a][3][1]), fmaxf(s[a][3][2], s[a][3][3]));
      float v = fmaxf(fmaxf(t0, t1), fmaxf(t2, t3));
      v = fmaxf(v, __shfl_xor(v, 16, 64));
      v = fmaxf(v, __shfl_xor(v, 32, 64));
      if (!__all(v <= mrun[a] + 8.f)) {
        const float mnew = fmaxf(mrun[a], v);
        const float corr = ex2(mrun[a] - mnew);
        mrun[a] = mnew;
#pragma unroll
        for (int n = 0; n < 4; ++n)
#pragma unroll
          for (int r = 0; r < 4; ++r) po[a][n][r] *= corr;
#pragma unroll
        for (int r = 0; r < 4; ++r) po_s[a][r] *= corr;
      }
#pragma unroll
      for (int sub = 0; sub < 4; ++sub) {
        bf16x4 pk;
#pragma unroll
        for (int r = 0; r < 4; ++r) pk[r] = (bf16_t)ex2(s[a][sub][r] - mrun[a]);
        *reinterpret_cast<bf16x4*>(&P[a * 16 + l15][sub * 16 + l4 * 4]) = pk;
      }
    }
#pragma unroll
    for (int a = 0; a < 2; ++a)
#pragma unroll
      for (int kk = 0; kk < 2; ++kk) {
        const bf16x8 pf =
            *reinterpret_cast<const bf16x8*>(&P[a * 16 + l15][kk * 32 + l4 * 8]);
        __builtin_amdgcn_s_setprio(1);
#pragma unroll
        for (int n = 0; n < 4; ++n) po[a][n] = mfma16(vf[kk][n], pf, po[a][n]);
        po_s[a] = mfma16(ones, pf, po_s[a]);
        __builtin_amdgcn_s_setprio(0);
      }
  }
#pragma unroll
  for (int a = 0; a < 2; ++a) {
    const float inv = 1.f / po_s[a][0];
#pragma unroll
    for (int n = 0; n < 4; ++n) {
      bf16x4 ov;
#pragma unroll
      for (int r = 0; r < 4; ++r) ov[r] = (bf16_t)(po[a][n][r] * inv);
      *reinterpret_cast<bf16x4*>(
          O + (size_t)(b * kT + qr0 + a * 16 + l15) * kC + h * kHD + n * 16 + l4 * 4) = ov;
    }
  }
}

// ---------------- launcher ----------------
extern "C" void kernel_launch(void* const* d_in, const int* in_sizes, int n_in,
                              void* d_out, int out_size, void* d_ws, size_t ws_size,
                              hipStream_t stream) {
  const float* x      = (const float*)d_in[0];
  const float* enc    = (const float*)d_in[1];
  const float* sa_wq  = (const float*)d_in[2];
  const float* sa_wk  = (const float*)d_in[3];
  const float* sa_wv  = (const float*)d_in[4];
  const float* sa_pw  = (const float*)d_in[5];
  const float* sa_pb  = (const float*)d_in[6];
  const float* ca_wq  = (const float*)d_in[7];
  const float* ca_wk  = (const float*)d_in[8];
  const float* ca_wv  = (const float*)d_in[9];
  const float* ca_pw  = (const float*)d_in[10];
  const float* ca_pb  = (const float*)d_in[11];
  const float* ff_w1  = (const float*)d_in[12];
  const float* ff_b1  = (const float*)d_in[13];
  const float* ff_w2  = (const float*)d_in[14];
  const float* ff_b2  = (const float*)d_in[15];
  const float* ln1_g  = (const float*)d_in[16];
  const float* ln1_b  = (const float*)d_in[17];
  const float* ln2_g  = (const float*)d_in[18];
  const float* ln2_b  = (const float*)d_in[19];
  const float* ln3_g  = (const float*)d_in[20];
  const float* ln3_b  = (const float*)d_in[21];

  const size_t ACT_BF = (size_t)kM * kC * 2;   // 16 MiB
  const size_t ACT_F  = (size_t)kM * kC * 4;   // 32 MiB
  const size_t W_BF   = (size_t)kC * kC * 2;
  const size_t FF_BF  = (size_t)kC * kFF * 2;
  const size_t H_BF   = (size_t)kM * kFF * 2;

  char* ws = (char*)d_ws;
  size_t off = 0;
  auto alloc = [&](size_t bytes) {
    char* p = ws + off;
    off += (bytes + 255) & ~(size_t)255;
    return p;
  };
  bf16_t* xbf   = (bf16_t*)alloc(ACT_BF);
  bf16_t* encbf = (bf16_t*)alloc(ACT_BF);
  bf16_t* lnbuf = (bf16_t*)alloc(ACT_BF);
  bf16_t* wsaq  = (bf16_t*)alloc(W_BF);
  bf16_t* wsak  = (bf16_t*)alloc(W_BF);
  bf16_t* wsav  = (bf16_t*)alloc(W_BF);
  bf16_t* wsap  = (bf16_t*)alloc(W_BF);
  bf16_t* wcaq  = (bf16_t*)alloc(W_BF);
  bf16_t* wcak  = (bf16_t*)alloc(W_BF);
  bf16_t* wcav  = (bf16_t*)alloc(W_BF);
  bf16_t* wcap  = (bf16_t*)alloc(W_BF);
  bf16_t* wff1t = (bf16_t*)alloc(FF_BF);   // [4096][1024]
  bf16_t* wff2t = (bf16_t*)alloc(FF_BF);   // [1024][4096]
  float*  rbuf  = (float*)alloc(ACT_F);    // residual chain (f32)
  char*   scr   = alloc(5 * ACT_BF > H_BF ? 5 * ACT_BF : H_BF);
  bf16_t* qbf   = (bf16_t*)scr;
  bf16_t* kbf   = (bf16_t*)(scr + ACT_BF);
  bf16_t* vtbf  = (bf16_t*)(scr + 3 * ACT_BF);
  bf16_t* aobf  = (bf16_t*)(scr + 4 * ACT_BF);
  bf16_t* hbf   = (bf16_t*)scr;            // FFN hidden reuses q..ao region

  const dim3 blk512(512), blk256(256), blk64(64), blkT(32, 8);
  const int n4 = kM * kC / 4;
  const dim3 gGemmC(kC / 256, kM / 128);    // (4, 64) = 256 blocks
  const dim3 gGemmF(kFF / 256, kM / 128);   // (16, 64)
  const dim3 gAttn(kB, kH, kT / 32);        // (8, 16, 32)
  const uint32_t LDSB = 147456;             // 144KB dynamic LDS for k_gemm2

  hipFuncSetAttribute((const void*)k_gemm2<0>, hipFuncAttributeMaxDynamicSharedMemorySize, LDSB);
  hipFuncSetAttribute((const void*)k_gemm2<1>, hipFuncAttributeMaxDynamicSharedMemorySize, LDSB);
  hipFuncSetAttribute((const void*)k_gemm2<2>, hipFuncAttributeMaxDynamicSharedMemorySize, LDSB);
  hipFuncSetAttribute((const void*)k_gemm2<3>, hipFuncAttributeMaxDynamicSharedMemorySize, LDSB);

  // ---- input casts + weight transposes ----
  k_cast_bf16<<<n4 / 256, blk256, 0, stream>>>(enc, encbf, n4);
  k_transpose_cast<<<dim3(kC / 32, kC / 32), blkT, 0, stream>>>(sa_wq, wsaq, kC, kC);
  k_transpose_cast<<<dim3(kC / 32, kC / 32), blkT, 0, stream>>>(sa_wk, wsak, kC, kC);
  k_transpose_cast<<<dim3(kC / 32, kC / 32), blkT, 0, stream>>>(sa_wv, wsav, kC, kC);
  k_transpose_cast<<<dim3(kC / 32, kC / 32), blkT, 0, stream>>>(sa_pw, wsap, kC, kC);
  k_transpose_cast<<<dim3(kC / 32, kC / 32), blkT, 0, stream>>>(ca_wq, wcaq, kC, kC);
  k_transpose_cast<<<dim3(kC / 32, kC / 32), blkT, 0, stream>>>(ca_wk, wcak, kC, kC);
  k_transpose_cast<<<dim3(kC / 32, kC / 32), blkT, 0, stream>>>(ca_wv, wcav, kC, kC);
  k_transpose_cast<<<dim3(kC / 32, kC / 32), blkT, 0, stream>>>(ca_pw, wcap, kC, kC);
  k_transpose_cast<<<dim3(kFF / 32, kC / 32), blkT, 0, stream>>>(ff_w1, wff1t, kC, kFF);
  k_transpose_cast<<<dim3(kC / 32, kFF / 32), blkT, 0, stream>>>(ff_w2, wff2t, kFF, kC);

  // ---- self-attention (q from ln1(x), k/v from raw x, causal) ----
  k_ln<true><<<kM, blk256, 0, stream>>>(x, ln1_g, ln1_b, lnbuf, xbf);
  k_gemm2<0><<<gGemmC, blk512, LDSB, stream>>>(lnbuf, wsaq, nullptr, nullptr, nullptr, qbf, kM, kC, kC);
  k_gemm2<0><<<gGemmC, blk512, LDSB, stream>>>(xbf,   wsak, nullptr, nullptr, nullptr, kbf, kM, kC, kC);
  k_gemm2<3><<<gGemmC, blk512, LDSB, stream>>>(xbf,   wsav, nullptr, nullptr, nullptr, vtbf, kM, kC, kC);
  k_attn<true><<<gAttn, blk64, 0, stream>>>(qbf, kbf, vtbf, aobf);
  k_gemm2<1><<<gGemmC, blk512, LDSB, stream>>>(aobf, wsap, sa_pb, x, rbuf, nullptr, kM, kC, kC);

  // ---- cross-attention (q from ln2(r), k/v from encoder_output) ----
  k_ln<false><<<kM, blk256, 0, stream>>>(rbuf, ln2_g, ln2_b, lnbuf, nullptr);
  k_gemm2<0><<<gGemmC, blk512, LDSB, stream>>>(lnbuf, wcaq, nullptr, nullptr, nullptr, qbf, kM, kC, kC);
  k_gemm2<0><<<gGemmC, blk512, LDSB, stream>>>(encbf, wcak, nullptr, nullptr, nullptr, kbf, kM, kC, kC);
  k_gemm2<3><<<gGemmC, blk512, LDSB, stream>>>(encbf, wcav, nullptr, nullptr, nullptr, vtbf, kM, kC, kC);
  k_attn<false><<<gAttn, blk64, 0, stream>>>(qbf, kbf, vtbf, aobf);
  k_gemm2<1><<<gGemmC, blk512, LDSB, stream>>>(aobf, wcap, ca_pb, rbuf, rbuf, nullptr, kM, kC, kC);

  // ---- feed-forward ----
  k_ln<false><<<kM, blk256, 0, stream>>>(rbuf, ln3_g, ln3_b, lnbuf, nullptr);
  k_gemm2<2><<<gGemmF, blk512, LDSB, stream>>>(lnbuf, wff1t, ff_b1, nullptr, nullptr, hbf, kM, kFF, kC);
  k_gemm2<1><<<gGemmC, blk512, LDSB, stream>>>(hbf, wff2t, ff_b2, rbuf, (float*)d_out, nullptr, kM, kC, kFF);

  (void)in_sizes; (void)n_in; (void)out_size; (void)ws_size;
}

// Round 7
// 611.879 us; speedup vs baseline: 1.1508x; 1.0035x over previous
//
#include <hip/hip_runtime.h>
#include <stdint.h>
#include <stddef.h>

typedef __bf16 bf16_t;
typedef __bf16 bf16x4 __attribute__((ext_vector_type(4)));
typedef __bf16 bf16x8 __attribute__((ext_vector_type(8)));
typedef float f32x4 __attribute__((ext_vector_type(4)));

#define DEV static __device__ __forceinline__

static constexpr int kB = 8, kT = 1024, kC = 1024, kM = 8192, kH = 16, kHD = 64, kFF = 4096;

DEV f32x4 mfma16(bf16x8 a, bf16x8 b, f32x4 c) {
  return __builtin_amdgcn_mfma_f32_16x16x32_bf16(a, b, c, 0, 0, 0);
}

// raw hardware exp2 (D = 2^S0); inputs always <= 0 here.
DEV float ex2(float x) {
  float r;
  asm("v_exp_f32 %0, %1" : "=v"(r) : "v"(x));
  return r;
}

// async global->LDS, 16B per lane. LDS dest must be wave-uniform base (+lane*16 by HW).
DEV void gload_lds16(const void* g, void* l) {
  __builtin_amdgcn_global_load_lds(
      reinterpret_cast<const __attribute__((address_space(1))) void*>(
          reinterpret_cast<uintptr_t>(g)),
      reinterpret_cast<__attribute__((address_space(3))) void*>(
          static_cast<uint32_t>(reinterpret_cast<uintptr_t>(l))),
      16, 0, 0);
}

// ---------------- cast f32 -> bf16 ----------------
__global__ void k_cast_bf16(const float* __restrict__ in, bf16_t* __restrict__ out, int n4) {
  int i = blockIdx.x * blockDim.x + threadIdx.x;
  if (i >= n4) return;
  float4 v = reinterpret_cast<const float4*>(in)[i];
  bf16x4 o;
  o[0] = (bf16_t)v.x; o[1] = (bf16_t)v.y; o[2] = (bf16_t)v.z; o[3] = (bf16_t)v.w;
  reinterpret_cast<bf16x4*>(out)[i] = o;
}

// ---------- transpose+cast f32[R][C] -> bf16[C][R] ----------
__global__ void k_transpose_cast(const float* __restrict__ in, bf16_t* __restrict__ out,
                                 int R, int C) {
  __shared__ float tile[32][33];
  int c0 = blockIdx.x * 32, r0 = blockIdx.y * 32;
  int tx = threadIdx.x, ty = threadIdx.y;  // (32,8)
#pragma unroll
  for (int i = 0; i < 4; ++i)
    tile[ty + 8 * i][tx] = in[(size_t)(r0 + ty + 8 * i) * C + c0 + tx];
  __syncthreads();
#pragma unroll
  for (int i = 0; i < 4; ++i)
    out[(size_t)(c0 + ty + 8 * i) * R + r0 + tx] = (bf16_t)tile[tx][ty + 8 * i];
}

// ---------------- layernorm f32 -> bf16 (one block per row of 1024) ----------------
template <bool CASTX>
__global__ __launch_bounds__(256) void k_ln(const float* __restrict__ in,
                                            const float* __restrict__ g,
                                            const float* __restrict__ b,
                                            bf16_t* __restrict__ out,
                                            bf16_t* __restrict__ rawout) {
  int row = blockIdx.x, t = threadIdx.x;
  const float4 v = reinterpret_cast<const float4*>(in + (size_t)row * kC)[t];
  if constexpr (CASTX) {
    bf16x4 c;
    c[0] = (bf16_t)v.x; c[1] = (bf16_t)v.y; c[2] = (bf16_t)v.z; c[3] = (bf16_t)v.w;
    reinterpret_cast<bf16x4*>(rawout + (size_t)row * kC)[t] = c;
  }
  float s = v.x + v.y + v.z + v.w;
  float ss = v.x * v.x + v.y * v.y + v.z * v.z + v.w * v.w;
#pragma unroll
  for (int off = 1; off < 64; off <<= 1) {
    s += __shfl_xor(s, off, 64);
    ss += __shfl_xor(ss, off, 64);
  }
  __shared__ float rs[4], rss[4];
  int w = t >> 6;
  if ((t & 63) == 0) { rs[w] = s; rss[w] = ss; }
  __syncthreads();
  s = rs[0] + rs[1] + rs[2] + rs[3];
  ss = rss[0] + rss[1] + rss[2] + rss[3];
  float mean = s * (1.f / kC);
  float var = ss * (1.f / kC) - mean * mean;
  float rstd = rsqrtf(var + 1e-5f);
  float4 gv = reinterpret_cast<const float4*>(g)[t];
  float4 bv = reinterpret_cast<const float4*>(b)[t];
  bf16x4 o;
  o[0] = (bf16_t)((v.x - mean) * rstd * gv.x + bv.x);
  o[1] = (bf16_t)((v.y - mean) * rstd * gv.y + bv.y);
  o[2] = (bf16_t)((v.z - mean) * rstd * gv.z + bv.z);
  o[3] = (bf16_t)((v.w - mean) * rstd * gv.w + bv.w);
  reinterpret_cast<bf16x4*>(out + (size_t)row * kC)[t] = o;
}

// ============ GEMM v2: C[M,N] = A[M,K] @ Bt[N,K]^T ============
// BM=128, BN=256, BK=64, 8 waves (2Mx4N, 64x64 each), ring-3 LDS (144KB dynamic),
// counted-vmcnt pipeline (stage t+2 while computing t, s_waitcnt vmcnt(6)), XOR-swizzled
// LDS (both-sides involution).
// EPI: 0 = bf16 out; 1 = f32 out + bias + residual; 2 = bf16 out + bias + ReLU;
//      3 = bf16 transposed out (ld M); 4 = split KV: col<N/2 -> outb normal (ld N/2),
//          col>=N/2 -> outb2 transposed (ld M)
template <int EPI>
__global__ __launch_bounds__(512, 2) void k_gemm2(
    const bf16_t* __restrict__ A, const bf16_t* __restrict__ Bt,
    const float* __restrict__ bias, const float* __restrict__ res,
    float* __restrict__ outf, bf16_t* __restrict__ outb, bf16_t* __restrict__ outb2,
    int M, int N, int K) {
  extern __shared__ bf16_t smem[];
  bf16_t* As = smem;                  // 3 x 128x64  (8192 el / buf)
  bf16_t* Bs = smem + 3 * 8192;       // 3 x 256x64  (16384 el / buf)
  const int t = threadIdx.x;
  const int w = t >> 6, lane = t & 63;
  const int l15 = lane & 15, l4 = lane >> 4;
  const int wr = w >> 2, wc = w & 3;
  const int bm0 = blockIdx.y * 128, bn0 = blockIdx.x * 256;

  f32x4 acc[4][4] = {};

  const int srow = w * 8 + (lane >> 3);
  const int scol = ((lane & 7) ^ (lane >> 3)) * 8;
  const bf16_t* aSrc0 = A + (size_t)(bm0 + srow) * K + scol;
  const bf16_t* bSrc0 = Bt + (size_t)(bn0 + srow) * K + scol;
  const size_t r64 = (size_t)64 * K;

  const int arow = wr * 64 + l15;
  const int brow = wc * 64 + l15;
  const int cbx = (l15 & 7) * 16;
  const int cbe0 = ((l4 * 16) ^ cbx) >> 1;
  const int cbe1 = ((64 | (l4 * 16)) ^ cbx) >> 1;

  const int nkt = K >> 6;

  auto stage = [&](int tt, int bi) {
    const size_t ko = (size_t)tt * 64;
    bf16_t* da = As + bi * 8192;
    bf16_t* db = Bs + bi * 16384;
    gload_lds16(aSrc0 + ko,            da + w * 512);
    gload_lds16(aSrc0 + ko + r64,      da + 4096 + w * 512);
    gload_lds16(bSrc0 + ko,            db + w * 512);
    gload_lds16(bSrc0 + ko + r64,      db + 4096 + w * 512);
    gload_lds16(bSrc0 + ko + 2 * r64,  db + 8192 + w * 512);
    gload_lds16(bSrc0 + ko + 3 * r64,  db + 12288 + w * 512);
  };

  stage(0, 0);
  stage(1, 1);
  asm volatile("s_waitcnt vmcnt(6)" ::: "memory");
  __builtin_amdgcn_s_barrier();

  int bi = 0, bs = 2;
  for (int tt = 0; tt < nkt; ++tt) {
    if (tt + 2 < nkt) stage(tt + 2, bs);
    const bf16_t* bA = As + bi * 8192;
    const bf16_t* bB = Bs + bi * 16384;
    bf16x8 af[4], bfr[4];
#pragma unroll
    for (int m = 0; m < 4; ++m)
      af[m] = *reinterpret_cast<const bf16x8*>(&bA[(arow + m * 16) * 64 + cbe0]);
#pragma unroll
    for (int n = 0; n < 4; ++n)
      bfr[n] = *reinterpret_cast<const bf16x8*>(&bB[(brow + n * 16) * 64 + cbe0]);
    __builtin_amdgcn_s_setprio(1);
#pragma unroll
    for (int m = 0; m < 4; ++m)
#pragma unroll
      for (int n = 0; n < 4; ++n) acc[m][n] = mfma16(af[m], bfr[n], acc[m][n]);
    __builtin_amdgcn_s_setprio(0);
#pragma unroll
    for (int m = 0; m < 4; ++m)
      af[m] = *reinterpret_cast<const bf16x8*>(&bA[(arow + m * 16) * 64 + cbe1]);
#pragma unroll
    for (int n = 0; n < 4; ++n)
      bfr[n] = *reinterpret_cast<const bf16x8*>(&bB[(brow + n * 16) * 64 + cbe1]);
    __builtin_amdgcn_s_setprio(1);
#pragma unroll
    for (int m = 0; m < 4; ++m)
#pragma unroll
      for (int n = 0; n < 4; ++n) acc[m][n] = mfma16(af[m], bfr[n], acc[m][n]);
    __builtin_amdgcn_s_setprio(0);
    if (tt + 1 < nkt) {
      if (tt + 2 < nkt) asm volatile("s_waitcnt vmcnt(6)" ::: "memory");
      else              asm volatile("s_waitcnt vmcnt(0)" ::: "memory");
      __builtin_amdgcn_s_barrier();
    }
    bi = (bi == 2) ? 0 : bi + 1;
    bs = (bs == 2) ? 0 : bs + 1;
  }

  const int gm = bm0 + wr * 64 + l4 * 4;
  const int gn = bn0 + wc * 64 + l15;
  if constexpr (EPI == 0) {
#pragma unroll
    for (int m = 0; m < 4; ++m)
#pragma unroll
      for (int n = 0; n < 4; ++n)
#pragma unroll
        for (int r = 0; r < 4; ++r)
          outb[(size_t)(gm + m * 16 + r) * N + (gn + n * 16)] = (bf16_t)acc[m][n][r];
  } else if constexpr (EPI == 1) {
#pragma unroll
    for (int m = 0; m < 4; ++m)
#pragma unroll
      for (int n = 0; n < 4; ++n) {
        const int col = gn + n * 16;
        const float bv = bias[col];
#pragma unroll
        for (int r = 0; r < 4; ++r) {
          const size_t idx = (size_t)(gm + m * 16 + r) * N + col;
          outf[idx] = acc[m][n][r] + bv + res[idx];
        }
      }
  } else if constexpr (EPI == 2) {
#pragma unroll
    for (int m = 0; m < 4; ++m)
#pragma unroll
      for (int n = 0; n < 4; ++n) {
        const int col = gn + n * 16;
        const float bv = bias[col];
#pragma unroll
        for (int r = 0; r < 4; ++r) {
          float v = acc[m][n][r] + bv;
          v = fmaxf(v, 0.f);
          outb[(size_t)(gm + m * 16 + r) * N + col] = (bf16_t)v;
        }
      }
  } else if constexpr (EPI == 3) {
#pragma unroll
    for (int m = 0; m < 4; ++m)
#pragma unroll
      for (int n = 0; n < 4; ++n) {
        bf16x4 ov;
#pragma unroll
        for (int r = 0; r < 4; ++r) ov[r] = (bf16_t)acc[m][n][r];
        *reinterpret_cast<bf16x4*>(&outb[(size_t)(gn + n * 16) * M + gm + m * 16]) = ov;
      }
  } else {  // EPI == 4: split KV (block-uniform branch: bn0 multiple of 256)
    const int half = N >> 1;
    if (bn0 < half) {
#pragma unroll
      for (int m = 0; m < 4; ++m)
#pragma unroll
        for (int n = 0; n < 4; ++n)
#pragma unroll
          for (int r = 0; r < 4; ++r)
            outb[(size_t)(gm + m * 16 + r) * half + (gn + n * 16)] = (bf16_t)acc[m][n][r];
    } else {
#pragma unroll
      for (int m = 0; m < 4; ++m)
#pragma unroll
        for (int n = 0; n < 4; ++n) {
          bf16x4 ov;
#pragma unroll
          for (int r = 0; r < 4; ++r) ov[r] = (bf16_t)acc[m][n][r];
          *reinterpret_cast<bf16x4*>(
              &outb2[(size_t)(gn + n * 16 - half) * M + gm + m * 16]) = ov;
        }
    }
  }
}

// ---------------- flash attention (swapped-operand, 2-deep K register pipeline) --------
// Grid (b, h, qi): one 64-lane wave per block, 32 q-rows, 64-key tiles.
// K(t+1) loads issued at top of tile t into the alternate named buffer (kfA/kfB,
// static indexing) -> K latency hides under tile t's softmax+PV. V issue-early as before.
template <bool CAUSAL>
__global__ __launch_bounds__(64) void k_attn(const bf16_t* __restrict__ Q,
                                             const bf16_t* __restrict__ Kb,
                                             const bf16_t* __restrict__ Vt,
                                             bf16_t* __restrict__ O) {
  __shared__ bf16_t P[32][72];  // P buffer: [q-row][key], 144B rows
  const int b = blockIdx.x, h = blockIdx.y, qi = blockIdx.z;
  const int lane = threadIdx.x;
  const int l15 = lane & 15, l4 = lane >> 4;
  const int qr0 = qi * 32;

  bf16x8 qf[2][2];
#pragma unroll
  for (int a = 0; a < 2; ++a) {
    const bf16_t* qp = Q + (size_t)(b * kT + qr0 + a * 16 + l15) * kC + h * kHD + l4 * 8;
    qf[a][0] = *reinterpret_cast<const bf16x8*>(qp);
    qf[a][1] = *reinterpret_cast<const bf16x8*>(qp + 32);
#pragma unroll
    for (int j = 0; j < 8; ++j) {
      qf[a][0][j] = (bf16_t)((float)qf[a][0][j] * 0.1803368801111204f);
      qf[a][1][j] = (bf16_t)((float)qf[a][1][j] * 0.1803368801111204f);
    }
  }
  bf16x8 ones;
#pragma unroll
  for (int j = 0; j < 8; ++j) ones[j] = (bf16_t)1.0f;

  f32x4 po[2][4] = {};
  f32x4 po_s[2] = {};
  float mrun[2];
  mrun[0] = mrun[1] = -3.0e38f;

  const int nkt = CAUSAL ? (qr0 + 31) / 64 + 1 : (kT / 64);
  const bf16_t* kp = Kb + (size_t)(b * kT + l15) * kC + h * kHD + l4 * 8;
  const bf16_t* vp0 = Vt + (size_t)(h * kHD + l15) * (kB * kT) + (size_t)b * kT + l4 * 8;

  auto kload = [&](bf16x8 (&kf)[4][2], int kt) {
    const bf16_t* p = kp + (size_t)kt * 64 * kC;
#pragma unroll
    for (int sub = 0; sub < 4; ++sub) {
      kf[sub][0] = *reinterpret_cast<const bf16x8*>(p + (size_t)sub * 16 * kC);
      kf[sub][1] = *reinterpret_cast<const bf16x8*>(p + (size_t)sub * 16 * kC + 32);
    }
  };

  auto tile = [&](const bf16x8 (&kf)[4][2], int kt) {
    // V fragments — issue first so latency hides under QK+softmax
    const bf16_t* vp = vp0 + (size_t)kt * 64;
    bf16x8 vf[2][4];
#pragma unroll
    for (int kk = 0; kk < 2; ++kk)
#pragma unroll
      for (int n = 0; n < 4; ++n)
        vf[kk][n] = *reinterpret_cast<const bf16x8*>(
            vp + (size_t)(n * 16) * (kB * kT) + kk * 32);

    f32x4 s[2][4] = {};
    __builtin_amdgcn_s_setprio(1);
#pragma unroll
    for (int a = 0; a < 2; ++a)
#pragma unroll
      for (int sub = 0; sub < 4; ++sub) {
        s[a][sub] = mfma16(kf[sub][0], qf[a][0], s[a][sub]);
        s[a][sub] = mfma16(kf[sub][1], qf[a][1], s[a][sub]);
      }
    __builtin_amdgcn_s_setprio(0);
    if (CAUSAL && kt == nkt - 1) {
#pragma unroll
      for (int a = 0; a < 2; ++a) {
        const int qrow = qr0 + a * 16 + l15;
#pragma unroll
        for (int sub = 0; sub < 4; ++sub)
#pragma unroll
          for (int r = 0; r < 4; ++r) {
            const int key = kt * 64 + sub * 16 + l4 * 4 + r;
            if (key > qrow) s[a][sub][r] = -3.0e38f;
          }
      }
    }
#pragma unroll
    for (int a = 0; a < 2; ++a) {
      float t0 = fmaxf(fmaxf(s[a][0][0], s[a][0][1]), fmaxf(s[a][0][2], s[a][0][3]));
      float t1 = fmaxf(fmaxf(s[a][1][0], s[a][1][1]), fmaxf(s[a][1][2], s[a][1][3]));
      float t2 = fmaxf(fmaxf(s[a][2][0], s[a][2][1]), fmaxf(s[a][2][2], s[a][2][3]));
      float t3 = fmaxf(fmaxf(s[a][3][0], s[a][3][1]), fmaxf(s[a][3][2], s[a][3][3]));
      float v = fmaxf(fmaxf(t0, t1), fmaxf(t2, t3));
      v = fmaxf(v, __shfl_xor(v, 16, 64));
      v = fmaxf(v, __shfl_xor(v, 32, 64));
      if (!__all(v <= mrun[a] + 8.f)) {
        const float mnew = fmaxf(mrun[a], v);
        const float corr = ex2(mrun[a] - mnew);
        mrun[a] = mnew;
#pragma unroll
        for (int n = 0; n < 4; ++n)
#pragma unroll
          for (int r = 0; r < 4; ++r) po[a][n][r] *= corr;
#pragma unroll
        for (int r = 0; r < 4; ++r) po_s[a][r] *= corr;
      }
#pragma unroll
      for (int sub = 0; sub < 4; ++sub) {
        bf16x4 pk;
#pragma unroll
        for (int r = 0; r < 4; ++r) pk[r] = (bf16_t)ex2(s[a][sub][r] - mrun[a]);
        *reinterpret_cast<bf16x4*>(&P[a * 16 + l15][sub * 16 + l4 * 4]) = pk;
      }
    }
#pragma unroll
    for (int a = 0; a < 2; ++a)
#pragma unroll
      for (int kk = 0; kk < 2; ++kk) {
        const bf16x8 pf =
            *reinterpret_cast<const bf16x8*>(&P[a * 16 + l15][kk * 32 + l4 * 8]);
        __builtin_amdgcn_s_setprio(1);
#pragma unroll
        for (int n = 0; n < 4; ++n) po[a][n] = mfma16(vf[kk][n], pf, po[a][n]);
        po_s[a] = mfma16(ones, pf, po_s[a]);
        __builtin_amdgcn_s_setprio(0);
      }
  };

  bf16x8 kfA[4][2], kfB[4][2];
  kload(kfA, 0);
  int kt = 0;
  for (;;) {
    if (kt + 1 < nkt) kload(kfB, kt + 1);   // issue-early; consumed next tile
    tile(kfA, kt);
    if (++kt >= nkt) break;
    if (kt + 1 < nkt) kload(kfA, kt + 1);
    tile(kfB, kt);
    if (++kt >= nkt) break;
  }

#pragma unroll
  for (int a = 0; a < 2; ++a) {
    const float inv = 1.f / po_s[a][0];
#pragma unroll
    for (int n = 0; n < 4; ++n) {
      bf16x4 ov;
#pragma unroll
      for (int r = 0; r < 4; ++r) ov[r] = (bf16_t)(po[a][n][r] * inv);
      *reinterpret_cast<bf16x4*>(
          O + (size_t)(b * kT + qr0 + a * 16 + l15) * kC + h * kHD + n * 16 + l4 * 4) = ov;
    }
  }
}

// ---------------- launcher ----------------
extern "C" void kernel_launch(void* const* d_in, const int* in_sizes, int n_in,
                              void* d_out, int out_size, void* d_ws, size_t ws_size,
                              hipStream_t stream) {
  const float* x      = (const float*)d_in[0];
  const float* enc    = (const float*)d_in[1];
  const float* sa_wq  = (const float*)d_in[2];
  const float* sa_wk  = (const float*)d_in[3];
  const float* sa_wv  = (const float*)d_in[4];
  const float* sa_pw  = (const float*)d_in[5];
  const float* sa_pb  = (const float*)d_in[6];
  const float* ca_wq  = (const float*)d_in[7];
  const float* ca_wk  = (const float*)d_in[8];
  const float* ca_wv  = (const float*)d_in[9];
  const float* ca_pw  = (const float*)d_in[10];
  const float* ca_pb  = (const float*)d_in[11];
  const float* ff_w1  = (const float*)d_in[12];
  const float* ff_b1  = (const float*)d_in[13];
  const float* ff_w2  = (const float*)d_in[14];
  const float* ff_b2  = (const float*)d_in[15];
  const float* ln1_g  = (const float*)d_in[16];
  const float* ln1_b  = (const float*)d_in[17];
  const float* ln2_g  = (const float*)d_in[18];
  const float* ln2_b  = (const float*)d_in[19];
  const float* ln3_g  = (const float*)d_in[20];
  const float* ln3_b  = (const float*)d_in[21];

  const size_t ACT_BF = (size_t)kM * kC * 2;   // 16 MiB
  const size_t ACT_F  = (size_t)kM * kC * 4;   // 32 MiB
  const size_t W_BF   = (size_t)kC * kC * 2;
  const size_t FF_BF  = (size_t)kC * kFF * 2;
  const size_t H_BF   = (size_t)kM * kFF * 2;

  char* ws = (char*)d_ws;
  size_t off = 0;
  auto alloc = [&](size_t bytes) {
    char* p = ws + off;
    off += (bytes + 255) & ~(size_t)255;
    return p;
  };
  bf16_t* xbf   = (bf16_t*)alloc(ACT_BF);
  bf16_t* encbf = (bf16_t*)alloc(ACT_BF);
  bf16_t* lnbuf = (bf16_t*)alloc(ACT_BF);
  bf16_t* wsaq  = (bf16_t*)alloc(W_BF);
  bf16_t* wkvsa = (bf16_t*)alloc(2 * W_BF);  // [2048][1024]: wk^T rows, then wv^T rows
  bf16_t* wsap  = (bf16_t*)alloc(W_BF);
  bf16_t* wcaq  = (bf16_t*)alloc(W_BF);
  bf16_t* wkvca = (bf16_t*)alloc(2 * W_BF);
  bf16_t* wcap  = (bf16_t*)alloc(W_BF);
  bf16_t* wff1t = (bf16_t*)alloc(FF_BF);   // [4096][1024]
  bf16_t* wff2t = (bf16_t*)alloc(FF_BF);   // [1024][4096]
  float*  rbuf  = (float*)alloc(ACT_F);    // residual chain (f32)
  char*   scr   = alloc(5 * ACT_BF > H_BF ? 5 * ACT_BF : H_BF);
  bf16_t* qbf   = (bf16_t*)scr;
  bf16_t* kbf   = (bf16_t*)(scr + ACT_BF);
  bf16_t* vtbf  = (bf16_t*)(scr + 3 * ACT_BF);
  bf16_t* aobf  = (bf16_t*)(scr + 4 * ACT_BF);
  bf16_t* hbf   = (bf16_t*)scr;            // FFN hidden reuses q..ao region

  const dim3 blk512(512), blk256(256), blk64(64), blkT(32, 8);
  const int n4 = kM * kC / 4;
  const dim3 gGemmC(kC / 256, kM / 128);    // (4, 64)
  const dim3 gGemmKV(2 * kC / 256, kM / 128);  // (8, 64)
  const dim3 gGemmF(kFF / 256, kM / 128);   // (16, 64)
  const dim3 gAttn(kB, kH, kT / 32);        // (8, 16, 32)
  const uint32_t LDSB = 147456;             // 144KB dynamic LDS for k_gemm2

  hipFuncSetAttribute((const void*)k_gemm2<0>, hipFuncAttributeMaxDynamicSharedMemorySize, LDSB);
  hipFuncSetAttribute((const void*)k_gemm2<1>, hipFuncAttributeMaxDynamicSharedMemorySize, LDSB);
  hipFuncSetAttribute((const void*)k_gemm2<2>, hipFuncAttributeMaxDynamicSharedMemorySize, LDSB);
  hipFuncSetAttribute((const void*)k_gemm2<4>, hipFuncAttributeMaxDynamicSharedMemorySize, LDSB);

  // ---- input casts + weight transposes ----
  k_cast_bf16<<<n4 / 256, blk256, 0, stream>>>(enc, encbf, n4);
  k_transpose_cast<<<dim3(kC / 32, kC / 32), blkT, 0, stream>>>(sa_wq, wsaq, kC, kC);
  k_transpose_cast<<<dim3(kC / 32, kC / 32), blkT, 0, stream>>>(sa_wk, wkvsa, kC, kC);
  k_transpose_cast<<<dim3(kC / 32, kC / 32), blkT, 0, stream>>>(sa_wv, wkvsa + (size_t)kC * kC, kC, kC);
  k_transpose_cast<<<dim3(kC / 32, kC / 32), blkT, 0, stream>>>(sa_pw, wsap, kC, kC);
  k_transpose_cast<<<dim3(kC / 32, kC / 32), blkT, 0, stream>>>(ca_wq, wcaq, kC, kC);
  k_transpose_cast<<<dim3(kC / 32, kC / 32), blkT, 0, stream>>>(ca_wk, wkvca, kC, kC);
  k_transpose_cast<<<dim3(kC / 32, kC / 32), blkT, 0, stream>>>(ca_wv, wkvca + (size_t)kC * kC, kC, kC);
  k_transpose_cast<<<dim3(kC / 32, kC / 32), blkT, 0, stream>>>(ca_pw, wcap, kC, kC);
  k_transpose_cast<<<dim3(kFF / 32, kC / 32), blkT, 0, stream>>>(ff_w1, wff1t, kC, kFF);
  k_transpose_cast<<<dim3(kC / 32, kFF / 32), blkT, 0, stream>>>(ff_w2, wff2t, kFF, kC);

  // ---- self-attention (q from ln1(x), k/v from raw x, causal) ----
  k_ln<true><<<kM, blk256, 0, stream>>>(x, ln1_g, ln1_b, lnbuf, xbf);
  k_gemm2<0><<<gGemmC, blk512, LDSB, stream>>>(lnbuf, wsaq, nullptr, nullptr, nullptr, qbf, nullptr, kM, kC, kC);
  k_gemm2<4><<<gGemmKV, blk512, LDSB, stream>>>(xbf, wkvsa, nullptr, nullptr, nullptr, kbf, vtbf, kM, 2 * kC, kC);
  k_attn<true><<<gAttn, blk64, 0, stream>>>(qbf, kbf, vtbf, aobf);
  k_gemm2<1><<<gGemmC, blk512, LDSB, stream>>>(aobf, wsap, sa_pb, x, rbuf, nullptr, nullptr, kM, kC, kC);

  // ---- cross-attention (q from ln2(r), k/v from encoder_output) ----
  k_ln<false><<<kM, blk256, 0, stream>>>(rbuf, ln2_g, ln2_b, lnbuf, nullptr);
  k_gemm2<0><<<gGemmC, blk512, LDSB, stream>>>(lnbuf, wcaq, nullptr, nullptr, nullptr, qbf, nullptr, kM, kC, kC);
  k_gemm2<4><<<gGemmKV, blk512, LDSB, stream>>>(encbf, wkvca, nullptr, nullptr, nullptr, kbf, vtbf, kM, 2 * kC, kC);
  k_attn<false><<<gAttn, blk64, 0, stream>>>(qbf, kbf, vtbf, aobf);
  k_gemm2<1><<<gGemmC, blk512, LDSB, stream>>>(aobf, wcap, ca_pb, rbuf, rbuf, nullptr, nullptr, kM, kC, kC);

  // ---- feed-forward ----
  k_ln<false><<<kM, blk256, 0, stream>>>(rbuf, ln3_g, ln3_b, lnbuf, nullptr);
  k_gemm2<2><<<gGemmF, blk512, LDSB, stream>>>(lnbuf, wff1t, ff_b1, nullptr, nullptr, hbf, nullptr, kM, kFF, kC);
  k_gemm2<1><<<gGemmC, blk512, LDSB, stream>>>(hbf, wff2t, ff_b2, rbuf, (float*)d_out, nullptr, nullptr, kM, kC, kFF);

  (void)in_sizes; (void)n_in; (void)out_size; (void)ws_size;
}